// Round 6
// baseline (147.551 us; speedup 1.0000x reference)
//
#include <hip/hip_runtime.h>
#include <math.h>
#include <stdint.h>

// B=2, S=4096, H=4, D=32, C=64. SCALE=16 folded as 16*log2(e) into q (base-2 softmax).
//
// ws layout (bytes), total < 15 MB:
//   0    : qf fp32 [8][4096][32]   (raw q; standardized inside attn)
//   4 MB : kf fp32 [8][4096][32]   -> dead after norm; REUSED as o fp32 [8192][128]
//   8 MB : k_hi ushort [8][4096][32]
//   10 MB: k_lo ushort [8][4096][32]
//   12 MB: v_hi ushort [8][32][4096]
//   14 MB: psum fp32 [2][2][128][64] (128 KB)  -- per-block partial sums (no atomics)
//   14.125 MB: psq  fp32 (128 KB)
//   14.25 MB : qA[256], qB[256] fp32  (q standardize tables: y = x*A + B)

typedef __attribute__((ext_vector_type(8))) short short8;
typedef __attribute__((ext_vector_type(4))) float f32x4;
typedef __attribute__((ext_vector_type(16))) float f32x16;

#define QSCALE 23.083120654223414f /* 16 * log2(e) */

#if __has_builtin(__builtin_amdgcn_exp2f)
#define EXP2F(x) __builtin_amdgcn_exp2f(x)
#else
#define EXP2F(x) exp2f(x)
#endif

__device__ inline uint32_t pack_hilo(float y) {
  uint32_t uy = __float_as_uint(y);
  uint32_t hb = (uy + 0x7fffu + ((uy >> 16) & 1u)) >> 16;  // RNE bf16
  float hf = __uint_as_float(hb << 16);
  float r = y - hf;
  uint32_t ur = __float_as_uint(r);
  uint32_t lb = (ur + 0x7fffu + ((ur >> 16) & 1u)) >> 16;
  return (hb << 16) | (lb & 0xffffu);
}

__device__ inline ushort f32_to_bf16(float y) {
  uint32_t uy = __float_as_uint(y);
  return (ushort)((uy + 0x7fffu + ((uy >> 16) & 1u)) >> 16);
}

__device__ inline float bpermf(int addr, float v) {
  return __int_as_float(__builtin_amdgcn_ds_bpermute(addr, __float_as_int(v)));
}

// ---------------------------------------------------------------------------
// Kernel 1: qkv = input @ w_qkv. q,k -> fp32 [bh][s][32]; v -> bf16-hi ushort
// [bh][32][4096] via LDS transpose (coalesced 16B stores). Stat partials to
// unique slots.
__global__ __launch_bounds__(256) void qkv_kernel(const float* __restrict__ in,
                                                  const float* __restrict__ w,
                                                  float* __restrict__ qf,
                                                  float* __restrict__ kf,
                                                  ushort* __restrict__ vhg,
                                                  float* __restrict__ psum,
                                                  float* __restrict__ psq) {
  __shared__ float As[64][68];
  __shared__ float Bs[64][68];
  __shared__ float ssum[64], ssq[64];
  const int ctile = blockIdx.x % 6;
  const int stile = blockIdx.x / 6;
  const int tid = threadIdx.x;
  const int row0 = stile * 64;
  const int sel = ctile >> 1;  // 0=q 1=k 2=v  (block-uniform)

  if (tid < 64) { ssum[tid] = 0.f; ssq[tid] = 0.f; }
  for (int idx = tid; idx < 64 * 64; idx += 256) {
    int s = idx >> 6, c = idx & 63;
    As[s][c] = in[(size_t)(row0 + s) * 64 + c];
  }
  for (int idx = tid; idx < 64 * 64; idx += 256) {
    int c = idx >> 6, ch = idx & 63;
    Bs[c][ch] = w[(size_t)c * 384 + ctile * 64 + ch];
  }
  __syncthreads();

  const int ts = tid >> 4, tc = tid & 15;
  float acc[4][4] = {};
  for (int c = 0; c < 64; c += 4) {
    float4 av[4];
#pragma unroll
    for (int a = 0; a < 4; ++a) av[a] = *(const float4*)&As[ts * 4 + a][c];
    const float4 b0 = *(const float4*)&Bs[c + 0][tc * 4];
    const float4 b1 = *(const float4*)&Bs[c + 1][tc * 4];
    const float4 b2 = *(const float4*)&Bs[c + 2][tc * 4];
    const float4 b3 = *(const float4*)&Bs[c + 3][tc * 4];
    const float bm[4][4] = {{b0.x, b0.y, b0.z, b0.w},
                            {b1.x, b1.y, b1.z, b1.w},
                            {b2.x, b2.y, b2.z, b2.w},
                            {b3.x, b3.y, b3.z, b3.w}};
#pragma unroll
    for (int a = 0; a < 4; ++a) {
      const float aw[4] = {av[a].x, av[a].y, av[a].z, av[a].w};
#pragma unroll
      for (int j = 0; j < 4; ++j)
#pragma unroll
        for (int cc = 0; cc < 4; ++cc) acc[a][cc] = fmaf(aw[j], bm[j][cc], acc[a][cc]);
    }
  }

  const int b = row0 >> 12;
  const int sl = (row0 & 4095) + ts * 4;
  const int chg0 = ctile * 64 + tc * 4;

  if (sel < 2) {
    const int hd0 = chg0 & 127;
    const int h = hd0 >> 5, d0 = hd0 & 31;
    float* dst = (sel == 0 ? qf : kf) + ((size_t)(b * 4 + h) * 4096) * 32 + d0;
#pragma unroll
    for (int a = 0; a < 4; ++a) {
      float4 st = make_float4(acc[a][0], acc[a][1], acc[a][2], acc[a][3]);
      *(float4*)&dst[(size_t)(sl + a) * 32] = st;
    }
#pragma unroll
    for (int cc = 0; cc < 4; ++cc) {
      float sm = acc[0][cc] + acc[1][cc] + acc[2][cc] + acc[3][cc];
      float sq = acc[0][cc] * acc[0][cc] + acc[1][cc] * acc[1][cc] +
                 acc[2][cc] * acc[2][cc] + acc[3][cc] * acc[3][cc];
      atomicAdd(&ssum[tc * 4 + cc], sm);
      atomicAdd(&ssq[tc * 4 + cc], sq);
    }
    __syncthreads();
    if (tid < 64) {
      const int ch = (ctile & 1) * 64 + tid;
      const int idx = (((sel * 2 + b) * 128) + ch) * 64 + (stile & 63);
      psum[idx] = ssum[tid];
      psq[idx] = ssq[tid];
    }
  } else {
    // v: transpose acc through LDS (As is dead) -> coalesced 16B bf16 stores.
    __syncthreads();
    float* VT = &As[0][0];  // [64 ch][68]
#pragma unroll
    for (int cc = 0; cc < 4; ++cc)
      *(float4*)&VT[(tc * 4 + cc) * 68 + ts * 4] =
          make_float4(acc[0][cc], acc[1][cc], acc[2][cc], acc[3][cc]);
    __syncthreads();
#pragma unroll
    for (int t2 = 0; t2 < 2; ++t2) {
      const int lin = tid + t2 * 256;
      const int ch = lin >> 3, gg = lin & 7;  // 8 consecutive threads = one 128B row run
      const float4 f0 = *(const float4*)&VT[ch * 68 + gg * 8];
      const float4 f1 = *(const float4*)&VT[ch * 68 + gg * 8 + 4];
      uint4 pk;
      pk.x = (uint32_t)f32_to_bf16(f0.x) | ((uint32_t)f32_to_bf16(f0.y) << 16);
      pk.y = (uint32_t)f32_to_bf16(f0.z) | ((uint32_t)f32_to_bf16(f0.w) << 16);
      pk.z = (uint32_t)f32_to_bf16(f1.x) | ((uint32_t)f32_to_bf16(f1.y) << 16);
      pk.w = (uint32_t)f32_to_bf16(f1.z) | ((uint32_t)f32_to_bf16(f1.w) << 16);
      const int hd = (ctile * 64 + ch) & 127;
      const int h = hd >> 5, d = hd & 31;
      *(uint4*)&vhg[((size_t)(b * 4 + h) * 32 + d) * 4096 + (row0 & 4095) + gg * 8] = pk;
    }
  }
}

// ---------------------------------------------------------------------------
// Kernel 2: grid 129. Blocks 0..127: finalize k stats + standardize k ->
// k_hi/k_lo. Block 128: q stat tables qA/qB.
__global__ __launch_bounds__(256) void norm_kernel(const float* __restrict__ kf,
                                                   ushort* __restrict__ khg,
                                                   ushort* __restrict__ klg,
                                                   const float* __restrict__ psum,
                                                   const float* __restrict__ psq,
                                                   float* __restrict__ qA,
                                                   float* __restrict__ qB) {
  const int bx = blockIdx.x;
  const int tid = threadIdx.x;
  if (bx == 128) {
    const int base = (((tid >> 7) * 128) + (tid & 127)) * 64;
    float sm = 0.f, sq = 0.f;
#pragma unroll 8
    for (int e = 0; e < 64; ++e) {
      sm += psum[base + e];
      sq += psq[base + e];
    }
    const float mu = sm * (1.f / 4096.f);
    const float inv = rsqrtf(sq * (1.f / 4096.f) - mu * mu + 1e-5f) * QSCALE;
    qA[tid] = inv;
    qB[tid] = -mu * inv;
    return;
  }
  __shared__ float red[2][32][8];
  __shared__ float kA[32], kB[32];
  const int bh = bx >> 4;
  const int s0 = (bx & 15) * 256;
  {
    const int d = tid >> 3, p = tid & 7;
    const int base = ((2 + (bh >> 2)) * 128 + (bh & 3) * 32 + d) * 64 + p * 8;
    float sm = 0.f, sq = 0.f;
#pragma unroll
    for (int e = 0; e < 8; ++e) {
      sm += psum[base + e];
      sq += psq[base + e];
    }
    red[0][d][p] = sm;
    red[1][d][p] = sq;
  }
  __syncthreads();
  if (tid < 32) {
    float sm = 0.f, sq = 0.f;
#pragma unroll
    for (int e = 0; e < 8; ++e) {
      sm += red[0][tid][e];
      sq += red[1][tid][e];
    }
    const float mu = sm * (1.f / 4096.f);
    const float inv = rsqrtf(sq * (1.f / 4096.f) - mu * mu + 1e-5f);
    kA[tid] = inv;
    kB[tid] = -mu * inv;
  }
  __syncthreads();

  const int d0 = (tid & 7) * 4;
  const float A0 = kA[d0], A1 = kA[d0 + 1], A2 = kA[d0 + 2], A3 = kA[d0 + 3];
  const float B0 = kB[d0], B1 = kB[d0 + 1], B2 = kB[d0 + 2], B3 = kB[d0 + 3];
  const float* src = kf + ((size_t)bh * 4096 + s0) * 32;
  ushort* dh = khg + ((size_t)bh * 4096 + s0) * 32 + d0;
  ushort* dl = klg + ((size_t)bh * 4096 + s0) * 32 + d0;
#pragma unroll
  for (int i = 0; i < 8; ++i) {
    const int s = (tid + i * 256) >> 3;
    float4 x = *(const float4*)&src[(size_t)s * 32 + d0];
    float y[4] = {fmaf(x.x, A0, B0), fmaf(x.y, A1, B1), fmaf(x.z, A2, B2), fmaf(x.w, A3, B3)};
    ushort4 hi, lo;
    ushort* hp = (ushort*)&hi;
    ushort* lp = (ushort*)&lo;
#pragma unroll
    for (int e = 0; e < 4; ++e) {
      uint32_t pk = pack_hilo(y[e]);
      hp[e] = (ushort)(pk >> 16);
      lp[e] = (ushort)(pk & 0xffff);
    }
    *(ushort4*)&dh[(size_t)s * 32] = hi;
    *(ushort4*)&dl[(size_t)s * 32] = lo;
  }
}

// ---------------------------------------------------------------------------
// Kernel 3: flash attention, 32x32 MFMA, S^T-orientation.
// grid 512 = 8 bh * 64 i-tiles(64 i); 512 thr = 4 j-streams * 2 waves(32 i each).
//
// S^T = K·Q^T via mfma_f32_32x32x16_bf16: A = K rows (sigma-permuted physical
// rows), B = Q (k=d, n=i=lane&31). C: col=lane&31 (=i), row=(r&3)+8*(r>>2)+4*h2.
// sigma: logical j = 16t+8h+e stored at physical row p=(e&3)+8*(e>>2)+4h+16*(t&1),
// subtile u=t>>1 -> PV B-frag for j-block t is exactly C-regs r=e+8*(t&1) of
// subtile u: P never leaves the lane.
// LDS swizzles: K chunk ^= (p>>1)&2 (rows 64B); V chunk ^= d&7 (rows 128B).
__global__ __launch_bounds__(512, 4) void attn_kernel(const float* __restrict__ qf,
                                                      const float* __restrict__ qA,
                                                      const float* __restrict__ qB,
                                                      const ushort* __restrict__ khg,
                                                      const ushort* __restrict__ klg,
                                                      const ushort* __restrict__ vhg,
                                                      float* __restrict__ o) {
  __shared__ char lds[49152];  // 4 streams * 12288 B (KHI 4K | KLO 4K | VHI 4K)

  const int tid = threadIdx.x;
  const int strm = tid >> 7;
  const int st = tid & 127;
  const int wv = (tid >> 6) & 1;
  const int lane = tid & 63;
  const int pl = lane & 31;
  const int h2 = lane >> 5;
  const int bh = blockIdx.x >> 6;
  const int i0 = (blockIdx.x & 63) * 64;

  ushort* KHI = (ushort*)lds + strm * 6144;  // [64 rows][32 d] hi; +2048 lo; +4096 V

  // --- q: load fp32, standardize (x*A+B), hi/lo split.
  // B-frag dh: k = 16*dh + 8*h2 + e  -> q elems d in [16dh+8h2, +8)
  const int irow = i0 + wv * 32 + pl;
  const float* qptr = qf + ((size_t)bh * 4096 + irow) * 32;
  short8 qh0, ql0, qh1, ql1;
  {
    const int da = 8 * h2, db = 16 + 8 * h2;
    const float4 x0 = *(const float4*)(qptr + da);
    const float4 x1 = *(const float4*)(qptr + da + 4);
    const float4 x2 = *(const float4*)(qptr + db);
    const float4 x3 = *(const float4*)(qptr + db + 4);
    const float4 A0 = *(const float4*)&qA[bh * 32 + da];
    const float4 A1 = *(const float4*)&qA[bh * 32 + da + 4];
    const float4 A2 = *(const float4*)&qA[bh * 32 + db];
    const float4 A3 = *(const float4*)&qA[bh * 32 + db + 4];
    const float4 B0 = *(const float4*)&qB[bh * 32 + da];
    const float4 B1 = *(const float4*)&qB[bh * 32 + da + 4];
    const float4 B2 = *(const float4*)&qB[bh * 32 + db];
    const float4 B3 = *(const float4*)&qB[bh * 32 + db + 4];
    const float y0[8] = {fmaf(x0.x, A0.x, B0.x), fmaf(x0.y, A0.y, B0.y),
                         fmaf(x0.z, A0.z, B0.z), fmaf(x0.w, A0.w, B0.w),
                         fmaf(x1.x, A1.x, B1.x), fmaf(x1.y, A1.y, B1.y),
                         fmaf(x1.z, A1.z, B1.z), fmaf(x1.w, A1.w, B1.w)};
    const float y1[8] = {fmaf(x2.x, A2.x, B2.x), fmaf(x2.y, A2.y, B2.y),
                         fmaf(x2.z, A2.z, B2.z), fmaf(x2.w, A2.w, B2.w),
                         fmaf(x3.x, A3.x, B3.x), fmaf(x3.y, A3.y, B3.y),
                         fmaf(x3.z, A3.z, B3.z), fmaf(x3.w, A3.w, B3.w)};
#pragma unroll
    for (int j = 0; j < 8; ++j) {
      uint32_t p0 = pack_hilo(y0[j]);
      uint32_t p1 = pack_hilo(y1[j]);
      qh0[j] = (short)(p0 >> 16); ql0[j] = (short)(p0 & 0xffff);
      qh1[j] = (short)(p1 >> 16); ql1[j] = (short)(p1 & 0xffff);
    }
  }

  const int bp32 = (lane ^ 32) << 2;

  // --- staging: st covers items st and st+128 (item1 = item0 + const offsets)
  const int jr = st >> 2, ck = st & 3;  // logical j row, 16B d-chunk
  const int et = jr >> 4, eh = (jr >> 3) & 1, ee = jr & 7;
  const int pphys = (ee & 3) + 8 * (ee >> 2) + 4 * eh + 16 * (et & 1);
  const int rowp = (et >> 1) * 32 + pphys;          // physical row (subtile u = et>>1)
  const int ckp = ck ^ ((pphys >> 1) & 2);
  const ushort* ksrc = khg + ((size_t)bh * 4096 + jr) * 32 + ck * 8;
  const ushort* lsrc = klg + ((size_t)bh * 4096 + jr) * 32 + ck * 8;
  ushort* kdst = KHI + rowp * 32 + ckp * 8;         // item1: +1024 (j+32 -> row+32)
  const int dr = st >> 3, cv = st & 7;
  const ushort* vsrc = vhg + ((size_t)bh * 32 + dr) * 4096 + cv * 8;
  ushort* vdst = KHI + 4096 + dr * 64 + (cv ^ (dr & 7)) * 8;  // item1: +1024 (d+16)

  // --- loop-invariant LDS read offsets (ushort units, swizzles folded)
  const int sw = (pl >> 1) & 2;
  const int k00 = pl * 32 + (h2 ^ sw) * 8;          // dh0 chunk = h2
  const int k01 = pl * 32 + ((2 + h2) ^ sw) * 8;    // dh1 chunk = 2+h2
  int voff[4];
#pragma unroll
  for (int t = 0; t < 4; ++t) voff[t] = pl * 64 + ((2 * t + h2) ^ (pl & 7)) * 8;

  f32x16 oacc;
#pragma unroll
  for (int r = 0; r < 16; ++r) oacc[r] = 0.f;
  float m = -INFINITY, l = 0.f;

  for (int it = 0; it < 16; ++it) {
    const int j0 = strm * 1024 + it * 64;
    __syncthreads();
    {
      const uint4 ka0 = *(const uint4*)(ksrc + (size_t)j0 * 32);
      const uint4 ka1 = *(const uint4*)(ksrc + (size_t)j0 * 32 + 1024);
      const uint4 la0 = *(const uint4*)(lsrc + (size_t)j0 * 32);
      const uint4 la1 = *(const uint4*)(lsrc + (size_t)j0 * 32 + 1024);
      const uint4 va0 = *(const uint4*)(vsrc + j0);
      const uint4 va1 = *(const uint4*)(vsrc + j0 + 65536);
      *(uint4*)kdst = ka0;
      *(uint4*)(kdst + 1024) = ka1;
      *(uint4*)(kdst + 2048) = la0;
      *(uint4*)(kdst + 3072) = la1;
      *(uint4*)vdst = va0;
      *(uint4*)(vdst + 1024) = va1;
    }
    __syncthreads();

#pragma unroll
    for (int u = 0; u < 2; ++u) {
      const ushort* KB = KHI + u * 1024;
      const short8 kh0 = *(const short8*)(KB + k00);
      const short8 kh1 = *(const short8*)(KB + k01);
      const short8 kl0 = *(const short8*)(KB + 2048 + k00);
      const short8 kl1 = *(const short8*)(KB + 2048 + k01);
      f32x16 sc;
#pragma unroll
      for (int r = 0; r < 16; ++r) sc[r] = 0.f;
      sc = __builtin_amdgcn_mfma_f32_32x32x16_bf16(kh0, qh0, sc, 0, 0, 0);
      sc = __builtin_amdgcn_mfma_f32_32x32x16_bf16(kh1, qh1, sc, 0, 0, 0);
      sc = __builtin_amdgcn_mfma_f32_32x32x16_bf16(kh0, ql0, sc, 0, 0, 0);
      sc = __builtin_amdgcn_mfma_f32_32x32x16_bf16(kh1, ql1, sc, 0, 0, 0);
      sc = __builtin_amdgcn_mfma_f32_32x32x16_bf16(kl0, qh0, sc, 0, 0, 0);
      sc = __builtin_amdgcn_mfma_f32_32x32x16_bf16(kl1, qh1, sc, 0, 0, 0);

      // --- online softmax (base-2), i = lane&31, halves differ only in j
      float mx = sc[0];
#pragma unroll
      for (int r = 1; r < 16; ++r) mx = fmaxf(mx, sc[r]);
      mx = fmaxf(mx, bpermf(bp32, mx));
      const float mn = fmaxf(m, mx);
      const float al = EXP2F(m - mn);
      m = mn;
#pragma unroll
      for (int r = 0; r < 16; ++r) sc[r] = EXP2F(sc[r] - mn);
      float rs = 0.f;
#pragma unroll
      for (int r = 0; r < 16; ++r) rs += sc[r];
      rs += bpermf(bp32, rs);
      l = l * al + rs;
#pragma unroll
      for (int r = 0; r < 16; ++r) oacc[r] *= al;

      // --- P -> bf16 (truncation; bias comp in merge), fully in-lane
      uint32_t pk[8];
#pragma unroll
      for (int i = 0; i < 8; ++i)
        pk[i] = __builtin_amdgcn_perm(__float_as_uint(sc[2 * i + 1]),
                                      __float_as_uint(sc[2 * i]), 0x07060302u);
      union { uint32_t u4[4]; short8 s8; } p0, p1;
      p0.u4[0] = pk[0]; p0.u4[1] = pk[1]; p0.u4[2] = pk[2]; p0.u4[3] = pk[3];
      p1.u4[0] = pk[4]; p1.u4[1] = pk[5]; p1.u4[2] = pk[6]; p1.u4[3] = pk[7];

      // --- PV: O^T += V^T·P^T, j-blocks t=2u, 2u+1
      const short8 va0 = *(const short8*)(KHI + 4096 + voff[2 * u]);
      const short8 va1 = *(const short8*)(KHI + 4096 + voff[2 * u + 1]);
      oacc = __builtin_amdgcn_mfma_f32_32x32x16_bf16(va0, p0.s8, oacc, 0, 0, 0);
      oacc = __builtin_amdgcn_mfma_f32_32x32x16_bf16(va1, p1.s8, oacc, 0, 0, 0);
    }
  }

  // --- merge 4 streams in LDS; write o fp32 [b*4096+i][128]
  __syncthreads();
  float* OM = (float*)lds;             // [4*64][36]
  float* ML = (float*)(lds + 36864);   // [4][ m[64] | l[64] ]
  {
    float* om = OM + (size_t)(strm * 64 + wv * 32 + pl) * 36;
#pragma unroll
    for (int g = 0; g < 4; ++g)  // d = (r&3) + 8g + 4h2
      *(float4*)&om[4 * h2 + 8 * g] =
          make_float4(oacc[4 * g], oacc[4 * g + 1], oacc[4 * g + 2], oacc[4 * g + 3]);
    if (h2 == 0) {
      ML[strm * 128 + wv * 32 + pl] = m;
      ML[strm * 128 + 64 + wv * 32 + pl] = l;
    }
  }
  __syncthreads();
  const int b = bh >> 2, h = bh & 3;
#pragma unroll
  for (int pass = 0; pass < 4; ++pass) {
    const int idx = tid + pass * 512;
    const int i = idx >> 5, d = idx & 31;
    const float m0 = ML[i], m1 = ML[128 + i], m2 = ML[256 + i], m3 = ML[384 + i];
    const float l0 = ML[64 + i], l1 = ML[192 + i], l2 = ML[320 + i], l3 = ML[448 + i];
    const float M = fmaxf(fmaxf(m0, m1), fmaxf(m2, m3));
    const float w0 = EXP2F(m0 - M), w1 = EXP2F(m1 - M);
    const float w2 = EXP2F(m2 - M), w3 = EXP2F(m3 - M);
    const float L = l0 * w0 + l1 * w1 + l2 * w2 + l3 * w3;
    const float val = (OM[i * 36 + d] * w0 + OM[(64 + i) * 36 + d] * w1 +
                       OM[(128 + i) * 36 + d] * w2 + OM[(192 + i) * 36 + d] * w3) *
                      (1.001953125f / L);  // (1+2^-9): P truncation bias compensation
    o[((size_t)(b * 4096) + i0 + i) * 128 + h * 32 + d] = val;
  }
}

// ---------------------------------------------------------------------------
// Kernel 4: out = o(fp32) @ w_out + b_out. [8192,128]x[128,64]. 1024 blocks.
__global__ __launch_bounds__(256) void proj_kernel(const float* __restrict__ o,
                                                   const float* __restrict__ w,
                                                   const float* __restrict__ bias,
                                                   float* __restrict__ out) {
  __shared__ float wT[64 * 132];  // [col][c], 16B granule g = (c>>2)^((col>>3)&7)
  const int tid = threadIdx.x;
  for (int idx = tid; idx < 8192; idx += 256) {
    const int c = idx >> 6, col = idx & 63;
    const int g = (c >> 2) ^ ((col >> 3) & 7);
    wT[col * 132 + (g << 2) + (c & 3)] = w[idx];
  }
  __syncthreads();
  const int col = tid & 63;
  const int r = blockIdx.x * 8 + ((tid >> 6) << 1);
  const float* r0 = o + (size_t)r * 128;
  const float* r1 = r0 + 128;
  const int wbase = col * 132;
  const int gx = (col >> 3) & 7;
  float a0 = bias[col], a1 = a0;
  for (int c = 0; c < 128; c += 4) {
    const float4 x0 = *(const float4*)&r0[c];
    const float4 x1 = *(const float4*)&r1[c];
    const float4 wv = *(const float4*)&wT[wbase + ((((c >> 2) ^ gx)) << 2)];
    a0 = fmaf(x0.x, wv.x, a0); a0 = fmaf(x0.y, wv.y, a0);
    a0 = fmaf(x0.z, wv.z, a0); a0 = fmaf(x0.w, wv.w, a0);
    a1 = fmaf(x1.x, wv.x, a1); a1 = fmaf(x1.y, wv.y, a1);
    a1 = fmaf(x1.z, wv.z, a1); a1 = fmaf(x1.w, wv.w, a1);
  }
  out[(size_t)r * 64 + col] = a0;
  out[(size_t)(r + 1) * 64 + col] = a1;
}

// ---------------------------------------------------------------------------
extern "C" void kernel_launch(void* const* d_in, const int* in_sizes, int n_in,
                              void* d_out, int out_size, void* d_ws, size_t ws_size,
                              hipStream_t stream) {
  const float* input = (const float*)d_in[0];
  const float* w_qkv = (const float*)d_in[1];
  const float* w_out = (const float*)d_in[2];
  const float* b_out = (const float*)d_in[3];

  char* W = (char*)d_ws;
  float* qf = (float*)(W + 0);
  float* kf = (float*)(W + (4u << 20));   // reused as o fp32 after norm
  ushort* khg = (ushort*)(W + (8u << 20));
  ushort* klg = (ushort*)(W + (10u << 20));
  ushort* vhg = (ushort*)(W + (12u << 20));
  float* psum = (float*)(W + (14u << 20));
  float* psq = (float*)(W + (14u << 20) + (128u << 10));
  float* qA = (float*)(W + (14u << 20) + (256u << 10));
  float* qB = qA + 256;
  float* ob = kf;
  float* out = (float*)d_out;

  hipLaunchKernelGGL(qkv_kernel, dim3(768), dim3(256), 0, stream, input, w_qkv, qf, kf,
                     vhg, psum, psq);
  hipLaunchKernelGGL(norm_kernel, dim3(129), dim3(256), 0, stream, kf, khg, klg,
                     psum, psq, qA, qB);
  hipLaunchKernelGGL(attn_kernel, dim3(512), dim3(512), 0, stream, qf, qA, qB,
                     khg, klg, vhg, ob);
  hipLaunchKernelGGL(proj_kernel, dim3(1024), dim3(256), 0, stream, ob, w_out, b_out, out);
}

// Round 7
// 140.551 us; speedup vs baseline: 1.0498x; 1.0498x over previous
//
#include <hip/hip_runtime.h>
#include <math.h>
#include <stdint.h>

// B=2, S=4096, H=4, D=32, C=64. SCALE=16 folded as 16*log2(e) into q (base-2 softmax).
//
// ws layout (bytes), total ~18.3 MB:
//   0    : qf raw fp32 [8][4096][32]  -> dead after norm; REUSED as o fp32 [8192][128]
//   4 MB : kf raw fp32 [8][4096][32]
//   8 MB : kfr_hi ushort frag-major [8][128 jt][2 c][64 lane][8]   (sigma rows)
//   10 MB: kfr_lo ushort frag-major
//   12 MB: vfr    ushort frag-major [8][128 jt][2 c][64 lane][8]
//   14 MB: qfr_hi ushort frag-major [8][128 it][2 c][64 lane][8]   (std folded)
//   16 MB: qfr_lo ushort frag-major
//   18 MB: psum fp32 [2 sel][2 b][128 ch][64] (128 KB), psq (128 KB)

typedef __attribute__((ext_vector_type(8))) short short8;
typedef __attribute__((ext_vector_type(4))) float f32x4;
typedef __attribute__((ext_vector_type(16))) float f32x16;

#define QSCALE 23.083120654223414f /* 16 * log2(e) */

#if __has_builtin(__builtin_amdgcn_exp2f)
#define EXP2F(x) __builtin_amdgcn_exp2f(x)
#else
#define EXP2F(x) exp2f(x)
#endif

__device__ inline uint32_t pack_hilo(float y) {
  uint32_t uy = __float_as_uint(y);
  uint32_t hb = (uy + 0x7fffu + ((uy >> 16) & 1u)) >> 16;  // RNE bf16
  float hf = __uint_as_float(hb << 16);
  float r = y - hf;
  uint32_t ur = __float_as_uint(r);
  uint32_t lb = (ur + 0x7fffu + ((ur >> 16) & 1u)) >> 16;
  return (hb << 16) | (lb & 0xffffu);
}

__device__ inline ushort f32_to_bf16(float y) {
  uint32_t uy = __float_as_uint(y);
  return (ushort)((uy + 0x7fffu + ((uy >> 16) & 1u)) >> 16);
}

__device__ inline float bpermf(int addr, float v) {
  return __int_as_float(__builtin_amdgcn_ds_bpermute(addr, __float_as_int(v)));
}

__device__ inline short8 as_s8(uint4 v) {
  union { uint4 u; short8 s; } t;
  t.u = v;
  return t.s;
}

// ---------------------------------------------------------------------------
// Kernel 1: qkv = input @ w_qkv. q,k -> raw fp32 [bh][s][32]; v -> frag-major
// bf16 (A-operand layout for PV). Stat partials to unique slots.
__global__ __launch_bounds__(256) void qkv_kernel(const float* __restrict__ in,
                                                  const float* __restrict__ w,
                                                  float* __restrict__ qf,
                                                  float* __restrict__ kf,
                                                  ushort* __restrict__ vfr,
                                                  float* __restrict__ psum,
                                                  float* __restrict__ psq) {
  __shared__ float As[64][68];
  __shared__ float Bs[64][68];
  __shared__ float ssum[64], ssq[64];
  const int ctile = blockIdx.x % 6;
  const int stile = blockIdx.x / 6;
  const int tid = threadIdx.x;
  const int row0 = stile * 64;
  const int sel = ctile >> 1;  // 0=q 1=k 2=v  (block-uniform)

  if (tid < 64) { ssum[tid] = 0.f; ssq[tid] = 0.f; }
  for (int idx = tid; idx < 64 * 64; idx += 256) {
    int s = idx >> 6, c = idx & 63;
    As[s][c] = in[(size_t)(row0 + s) * 64 + c];
  }
  for (int idx = tid; idx < 64 * 64; idx += 256) {
    int c = idx >> 6, ch = idx & 63;
    Bs[c][ch] = w[(size_t)c * 384 + ctile * 64 + ch];
  }
  __syncthreads();

  const int ts = tid >> 4, tc = tid & 15;
  float acc[4][4] = {};
  for (int c = 0; c < 64; c += 4) {
    float4 av[4];
#pragma unroll
    for (int a = 0; a < 4; ++a) av[a] = *(const float4*)&As[ts * 4 + a][c];
    const float4 b0 = *(const float4*)&Bs[c + 0][tc * 4];
    const float4 b1 = *(const float4*)&Bs[c + 1][tc * 4];
    const float4 b2 = *(const float4*)&Bs[c + 2][tc * 4];
    const float4 b3 = *(const float4*)&Bs[c + 3][tc * 4];
    const float bm[4][4] = {{b0.x, b0.y, b0.z, b0.w},
                            {b1.x, b1.y, b1.z, b1.w},
                            {b2.x, b2.y, b2.z, b2.w},
                            {b3.x, b3.y, b3.z, b3.w}};
#pragma unroll
    for (int a = 0; a < 4; ++a) {
      const float aw[4] = {av[a].x, av[a].y, av[a].z, av[a].w};
#pragma unroll
      for (int j = 0; j < 4; ++j)
#pragma unroll
        for (int cc = 0; cc < 4; ++cc) acc[a][cc] = fmaf(aw[j], bm[j][cc], acc[a][cc]);
    }
  }

  const int b = row0 >> 12;
  const int sl = (row0 & 4095) + ts * 4;
  const int chg0 = ctile * 64 + tc * 4;

  if (sel < 2) {
    const int hd0 = chg0 & 127;
    const int h = hd0 >> 5, d0 = hd0 & 31;
    float* dst = (sel == 0 ? qf : kf) + ((size_t)(b * 4 + h) * 4096) * 32 + d0;
#pragma unroll
    for (int a = 0; a < 4; ++a) {
      float4 st = make_float4(acc[a][0], acc[a][1], acc[a][2], acc[a][3]);
      *(float4*)&dst[(size_t)(sl + a) * 32] = st;
    }
#pragma unroll
    for (int cc = 0; cc < 4; ++cc) {
      float sm = acc[0][cc] + acc[1][cc] + acc[2][cc] + acc[3][cc];
      float sq = acc[0][cc] * acc[0][cc] + acc[1][cc] * acc[1][cc] +
                 acc[2][cc] * acc[2][cc] + acc[3][cc] * acc[3][cc];
      atomicAdd(&ssum[tc * 4 + cc], sm);
      atomicAdd(&ssq[tc * 4 + cc], sq);
    }
    __syncthreads();
    if (tid < 64) {
      const int ch = (ctile & 1) * 64 + tid;
      const int idx = (((sel * 2 + b) * 128) + ch) * 64 + (stile & 63);
      psum[idx] = ssum[tid];
      psq[idx] = ssq[tid];
    }
  } else {
    // v -> frag-major: element (jt,c,lane,jj) = V[d=lane&31][j=32jt+16c+8(lane>>5)+jj]
    __syncthreads();
    float* VT = &As[0][0];  // [64 ch][68 s]
#pragma unroll
    for (int cc = 0; cc < 4; ++cc)
      *(float4*)&VT[(tc * 4 + cc) * 68 + ts * 4] =
          make_float4(acc[0][cc], acc[1][cc], acc[2][cc], acc[3][cc]);
    __syncthreads();
    const int jt0 = (row0 & 4095) >> 5;
#pragma unroll
    for (int hl = 0; hl < 2; ++hl) {
      const int jtl = tid >> 7, c = (tid >> 6) & 1, ln = tid & 63;
      const int d = ln & 31, hh = ln >> 5;
      const int jloc = 32 * jtl + 16 * c + 8 * hh;
      const int ch = hl * 32 + d;
      const float4 f0 = *(const float4*)&VT[ch * 68 + jloc];
      const float4 f1 = *(const float4*)&VT[ch * 68 + jloc + 4];
      uint4 pk;
      pk.x = (uint32_t)f32_to_bf16(f0.x) | ((uint32_t)f32_to_bf16(f0.y) << 16);
      pk.y = (uint32_t)f32_to_bf16(f0.z) | ((uint32_t)f32_to_bf16(f0.w) << 16);
      pk.z = (uint32_t)f32_to_bf16(f1.x) | ((uint32_t)f32_to_bf16(f1.y) << 16);
      pk.w = (uint32_t)f32_to_bf16(f1.z) | ((uint32_t)f32_to_bf16(f1.w) << 16);
      const int h = (ctile - 4) * 2 + hl;
      ushort* dst =
          vfr + (((size_t)((b * 4 + h) * 128 + jt0 + jtl) * 2 + c) * 64 + ln) * 8;
      *(uint4*)dst = pk;
    }
  }
}

// ---------------------------------------------------------------------------
// Kernel 2: finalize stats + pack q/k into frag-major hi/lo.
// grid 256: blocks 0..127 -> q (std * QSCALE, no sigma), 128..255 -> k (sigma rows).
// sigma (self-inverse bit swap 2<->3): phys row p holds logical j = swap23(p).
__global__ __launch_bounds__(256) void norm_kernel(const float* __restrict__ qf,
                                                   const float* __restrict__ kf,
                                                   ushort* __restrict__ qfr_hi,
                                                   ushort* __restrict__ qfr_lo,
                                                   ushort* __restrict__ kfr_hi,
                                                   ushort* __restrict__ kfr_lo,
                                                   const float* __restrict__ psum,
                                                   const float* __restrict__ psq) {
  const int bx = blockIdx.x;
  const int tensor = bx >> 7;  // 0 = q, 1 = k
  const int bh = (bx >> 4) & 7;
  const int s0 = (bx & 15) * 256;
  const int tid = threadIdx.x;
  __shared__ float red[2][32][8];
  __shared__ float tA[32], tB[32];
  {
    const int d = tid >> 3, p = tid & 7;
    const int base = ((tensor * 2 + (bh >> 2)) * 128 + (bh & 3) * 32 + d) * 64 + p * 8;
    float sm = 0.f, sq = 0.f;
#pragma unroll
    for (int e = 0; e < 8; ++e) {
      sm += psum[base + e];
      sq += psq[base + e];
    }
    red[0][d][p] = sm;
    red[1][d][p] = sq;
  }
  __syncthreads();
  if (tid < 32) {
    float sm = 0.f, sq = 0.f;
#pragma unroll
    for (int e = 0; e < 8; ++e) {
      sm += red[0][tid][e];
      sq += red[1][tid][e];
    }
    const float mu = sm * (1.f / 4096.f);
    const float scale = tensor == 0 ? QSCALE : 1.0f;
    const float inv = rsqrtf(sq * (1.f / 4096.f) - mu * mu + 1e-5f) * scale;
    tA[tid] = inv;
    tB[tid] = -mu * inv;
  }
  __syncthreads();

  const float* src = (tensor == 0 ? qf : kf) + (size_t)bh * 4096 * 32;
  ushort* dhi = (tensor == 0 ? qfr_hi : kfr_hi) + (size_t)(bh * 128 + (s0 >> 5)) * 1024;
  ushort* dlo = (tensor == 0 ? qfr_lo : kfr_lo) + (size_t)(bh * 128 + (s0 >> 5)) * 1024;
#pragma unroll
  for (int pass = 0; pass < 4; ++pass) {
    const int idx = tid + pass * 256;
    const int jtl = idx >> 7;
    const int c = (idx >> 6) & 1;
    const int ln = idx & 63;
    const int p = ln & 31, hh = ln >> 5;
    const int row = tensor == 0 ? p : ((p & 0x13) | ((p & 4) << 1) | ((p & 8) >> 1));
    const int s = s0 + 32 * jtl + row;
    const int d0 = 16 * c + 8 * hh;
    const float4 x0 = *(const float4*)&src[(size_t)s * 32 + d0];
    const float4 x1 = *(const float4*)&src[(size_t)s * 32 + d0 + 4];
    const float4 A0 = *(const float4*)&tA[d0];
    const float4 A1 = *(const float4*)&tA[d0 + 4];
    const float4 B0 = *(const float4*)&tB[d0];
    const float4 B1 = *(const float4*)&tB[d0 + 4];
    uint32_t pk[8];
    pk[0] = pack_hilo(fmaf(x0.x, A0.x, B0.x));
    pk[1] = pack_hilo(fmaf(x0.y, A0.y, B0.y));
    pk[2] = pack_hilo(fmaf(x0.z, A0.z, B0.z));
    pk[3] = pack_hilo(fmaf(x0.w, A0.w, B0.w));
    pk[4] = pack_hilo(fmaf(x1.x, A1.x, B1.x));
    pk[5] = pack_hilo(fmaf(x1.y, A1.y, B1.y));
    pk[6] = pack_hilo(fmaf(x1.z, A1.z, B1.z));
    pk[7] = pack_hilo(fmaf(x1.w, A1.w, B1.w));
    uint4 HV, LV;
    HV.x = __builtin_amdgcn_perm(pk[1], pk[0], 0x07060302u);
    HV.y = __builtin_amdgcn_perm(pk[3], pk[2], 0x07060302u);
    HV.z = __builtin_amdgcn_perm(pk[5], pk[4], 0x07060302u);
    HV.w = __builtin_amdgcn_perm(pk[7], pk[6], 0x07060302u);
    LV.x = __builtin_amdgcn_perm(pk[1], pk[0], 0x05040100u);
    LV.y = __builtin_amdgcn_perm(pk[3], pk[2], 0x05040100u);
    LV.z = __builtin_amdgcn_perm(pk[5], pk[4], 0x05040100u);
    LV.w = __builtin_amdgcn_perm(pk[7], pk[6], 0x05040100u);
    const size_t doff = ((size_t)(jtl * 2 + c) * 64 + ln) * 8;
    *(uint4*)(dhi + doff) = HV;
    *(uint4*)(dlo + doff) = LV;
  }
}

// ---------------------------------------------------------------------------
// Kernel 3: flash attention, 32x32 MFMA, zero-LDS barrier-free main loop.
// grid 512 (bh = bx&7 for XCD-L2 locality, itp = bx>>3); block 512 thr = 8 waves
// = 4 j-splits x 2 i-tiles. Wave: Q frags persistent, K/V frags streamed from
// global (frag-major, 1KB coalesced dwordx4), 1-deep register prefetch,
// 8 MFMAs + online softmax per 32x32 tile, 32 iters, NO loop barriers.
__global__ __launch_bounds__(512, 4) void attn_kernel(const ushort* __restrict__ qfr_hi,
                                                      const ushort* __restrict__ qfr_lo,
                                                      const ushort* __restrict__ kfr_hi,
                                                      const ushort* __restrict__ kfr_lo,
                                                      const ushort* __restrict__ vfr,
                                                      float* __restrict__ o) {
  __shared__ float OM[8 * 32 * 36];  // [wave][i 32][36] (d in 0..31)
  __shared__ float ML[8 * 64];       // [wave][ m[32] | l[32] ]

  const int tid = threadIdx.x;
  const int w = tid >> 6;
  const int js = w & 3;
  const int itl = w >> 2;
  const int lane = tid & 63;
  const int pl = lane & 31, h2 = lane >> 5;
  const int bh = blockIdx.x & 7;
  const int itp = blockIdx.x >> 3;
  const int it = itp * 2 + itl;

  // persistent Q frags (B-operand): element d = 16c + 8h2 + jj at col i
  const size_t qbase = (size_t)(bh * 128 + it) * 1024 + lane * 8;
  const short8 qh0 = *(const short8*)(qfr_hi + qbase);
  const short8 qh1 = *(const short8*)(qfr_hi + qbase + 512);
  const short8 ql0 = *(const short8*)(qfr_lo + qbase);
  const short8 ql1 = *(const short8*)(qfr_lo + qbase + 512);

  const int bp32 = (lane ^ 32) << 2;

  const size_t kbase = (size_t)(bh * 128 + js * 32) * 1024 + lane * 8;
  const ushort* kh = kfr_hi + kbase;
  const ushort* kl = kfr_lo + kbase;
  const ushort* vp = vfr + kbase;

  f32x16 oacc;
#pragma unroll
  for (int r = 0; r < 16; ++r) oacc[r] = 0.f;
  float m = -INFINITY, l = 0.f;

  uint4 rk0 = *(const uint4*)(kh);
  uint4 rk1 = *(const uint4*)(kh + 512);
  uint4 rl0 = *(const uint4*)(kl);
  uint4 rl1 = *(const uint4*)(kl + 512);
  uint4 rv0 = *(const uint4*)(vp);
  uint4 rv1 = *(const uint4*)(vp + 512);

  for (int t = 0; t < 32; ++t) {
    const short8 ck0 = as_s8(rk0), ck1 = as_s8(rk1);
    const short8 cl0 = as_s8(rl0), cl1 = as_s8(rl1);
    const short8 cv0 = as_s8(rv0), cv1 = as_s8(rv1);
    {  // prefetch t+1 (last iter reads in-bounds scratch, unused)
      const int off = (t + 1) * 1024;
      rk0 = *(const uint4*)(kh + off);
      rk1 = *(const uint4*)(kh + off + 512);
      rl0 = *(const uint4*)(kl + off);
      rl1 = *(const uint4*)(kl + off + 512);
      rv0 = *(const uint4*)(vp + off);
      rv1 = *(const uint4*)(vp + off + 512);
    }

    // --- S^T = K·Q^T (A = K sigma-rows, B = Q), split precision: 6 MFMAs
    f32x16 sc;
#pragma unroll
    for (int r = 0; r < 16; ++r) sc[r] = 0.f;
    sc = __builtin_amdgcn_mfma_f32_32x32x16_bf16(ck0, qh0, sc, 0, 0, 0);
    sc = __builtin_amdgcn_mfma_f32_32x32x16_bf16(ck1, qh1, sc, 0, 0, 0);
    sc = __builtin_amdgcn_mfma_f32_32x32x16_bf16(ck0, ql0, sc, 0, 0, 0);
    sc = __builtin_amdgcn_mfma_f32_32x32x16_bf16(ck1, ql1, sc, 0, 0, 0);
    sc = __builtin_amdgcn_mfma_f32_32x32x16_bf16(cl0, qh0, sc, 0, 0, 0);
    sc = __builtin_amdgcn_mfma_f32_32x32x16_bf16(cl1, qh1, sc, 0, 0, 0);

    // --- online softmax (base-2); col i = pl, 16 j in regs + 16 in h2-partner
    float mx = sc[0];
#pragma unroll
    for (int r = 1; r < 16; ++r) mx = fmaxf(mx, sc[r]);
    mx = fmaxf(mx, bpermf(bp32, mx));
    const float mn = fmaxf(m, mx);
    const float al = EXP2F(m - mn);
    m = mn;
#pragma unroll
    for (int r = 0; r < 16; ++r) sc[r] = EXP2F(sc[r] - mn);
    float rs = 0.f;
#pragma unroll
    for (int r = 0; r < 16; ++r) rs += sc[r];
    rs += bpermf(bp32, rs);
    l = l * al + rs;
#pragma unroll
    for (int r = 0; r < 16; ++r) oacc[r] *= al;

    // --- P -> bf16 (truncation; bias comp in merge); chunk c regs = 8c..8c+7
    uint32_t pk[8];
#pragma unroll
    for (int i = 0; i < 8; ++i)
      pk[i] = __builtin_amdgcn_perm(__float_as_uint(sc[2 * i + 1]),
                                    __float_as_uint(sc[2 * i]), 0x07060302u);
    union { uint32_t u4[4]; short8 s8; } p0, p1;
    p0.u4[0] = pk[0]; p0.u4[1] = pk[1]; p0.u4[2] = pk[2]; p0.u4[3] = pk[3];
    p1.u4[0] = pk[4]; p1.u4[1] = pk[5]; p1.u4[2] = pk[6]; p1.u4[3] = pk[7];

    // --- PV: O^T += V^T·P^T (A = V frag, B = P in-lane)
    oacc = __builtin_amdgcn_mfma_f32_32x32x16_bf16(cv0, p0.s8, oacc, 0, 0, 0);
    oacc = __builtin_amdgcn_mfma_f32_32x32x16_bf16(cv1, p1.s8, oacc, 0, 0, 0);
  }

  // --- merge 4 j-splits per i-tile in LDS; write o fp32 [b*4096+i][128]
  {
    float* om = OM + (size_t)(w * 32 + pl) * 36;
#pragma unroll
    for (int g = 0; g < 4; ++g)  // d = (r&3) + 8g + 4h2
      *(float4*)&om[4 * h2 + 8 * g] =
          make_float4(oacc[4 * g], oacc[4 * g + 1], oacc[4 * g + 2], oacc[4 * g + 3]);
    if (h2 == 0) {
      ML[w * 64 + pl] = m;
      ML[w * 64 + 32 + pl] = l;
    }
  }
  __syncthreads();
  const int b = bh >> 2, h = bh & 3;
#pragma unroll
  for (int pass = 0; pass < 4; ++pass) {
    const int idx = tid + pass * 512;  // 2048 outputs: [itl2 2][i 32][d 32]
    const int itl2 = idx >> 10;
    const int i = (idx >> 5) & 31;
    const int d = idx & 31;
    const int wb = itl2 * 4;
    const float m0 = ML[(wb + 0) * 64 + i], m1 = ML[(wb + 1) * 64 + i];
    const float m2 = ML[(wb + 2) * 64 + i], m3 = ML[(wb + 3) * 64 + i];
    const float l0 = ML[(wb + 0) * 64 + 32 + i], l1 = ML[(wb + 1) * 64 + 32 + i];
    const float l2 = ML[(wb + 2) * 64 + 32 + i], l3 = ML[(wb + 3) * 64 + 32 + i];
    const float M = fmaxf(fmaxf(m0, m1), fmaxf(m2, m3));
    const float w0 = EXP2F(m0 - M), w1 = EXP2F(m1 - M);
    const float w2 = EXP2F(m2 - M), w3 = EXP2F(m3 - M);
    const float L = l0 * w0 + l1 * w1 + l2 * w2 + l3 * w3;
    const float val = (OM[((wb + 0) * 32 + i) * 36 + d] * w0 +
                       OM[((wb + 1) * 32 + i) * 36 + d] * w1 +
                       OM[((wb + 2) * 32 + i) * 36 + d] * w2 +
                       OM[((wb + 3) * 32 + i) * 36 + d] * w3) *
                      (1.001953125f / L);  // (1+2^-9): P truncation bias comp
    const int ig = (itp * 2 + itl2) * 32 + i;
    o[((size_t)(b * 4096) + ig) * 128 + h * 32 + d] = val;
  }
}

// ---------------------------------------------------------------------------
// Kernel 4: out = o(fp32) @ w_out + b_out. [8192,128]x[128,64]. 1024 blocks.
__global__ __launch_bounds__(256) void proj_kernel(const float* __restrict__ o,
                                                   const float* __restrict__ w,
                                                   const float* __restrict__ bias,
                                                   float* __restrict__ out) {
  __shared__ float wT[64 * 132];  // [col][c], 16B granule g = (c>>2)^((col>>3)&7)
  const int tid = threadIdx.x;
  for (int idx = tid; idx < 8192; idx += 256) {
    const int c = idx >> 6, col = idx & 63;
    const int g = (c >> 2) ^ ((col >> 3) & 7);
    wT[col * 132 + (g << 2) + (c & 3)] = w[idx];
  }
  __syncthreads();
  const int col = tid & 63;
  const int r = blockIdx.x * 8 + ((tid >> 6) << 1);
  const float* r0 = o + (size_t)r * 128;
  const float* r1 = r0 + 128;
  const int wbase = col * 132;
  const int gx = (col >> 3) & 7;
  float a0 = bias[col], a1 = a0;
  for (int c = 0; c < 128; c += 4) {
    const float4 x0 = *(const float4*)&r0[c];
    const float4 x1 = *(const float4*)&r1[c];
    const float4 wv = *(const float4*)&wT[wbase + ((((c >> 2) ^ gx)) << 2)];
    a0 = fmaf(x0.x, wv.x, a0); a0 = fmaf(x0.y, wv.y, a0);
    a0 = fmaf(x0.z, wv.z, a0); a0 = fmaf(x0.w, wv.w, a0);
    a1 = fmaf(x1.x, wv.x, a1); a1 = fmaf(x1.y, wv.y, a1);
    a1 = fmaf(x1.z, wv.z, a1); a1 = fmaf(x1.w, wv.w, a1);
  }
  out[(size_t)r * 64 + col] = a0;
  out[(size_t)(r + 1) * 64 + col] = a1;
}

// ---------------------------------------------------------------------------
extern "C" void kernel_launch(void* const* d_in, const int* in_sizes, int n_in,
                              void* d_out, int out_size, void* d_ws, size_t ws_size,
                              hipStream_t stream) {
  const float* input = (const float*)d_in[0];
  const float* w_qkv = (const float*)d_in[1];
  const float* w_out = (const float*)d_in[2];
  const float* b_out = (const float*)d_in[3];

  char* W = (char*)d_ws;
  float* qf = (float*)(W + 0);              // raw q; reused as o after norm
  float* kf = (float*)(W + (4u << 20));     // raw k
  ushort* kfr_hi = (ushort*)(W + (8u << 20));
  ushort* kfr_lo = (ushort*)(W + (10u << 20));
  ushort* vfr = (ushort*)(W + (12u << 20));
  ushort* qfr_hi = (ushort*)(W + (14u << 20));
  ushort* qfr_lo = (ushort*)(W + (16u << 20));
  float* psum = (float*)(W + (18u << 20));
  float* psq = (float*)(W + (18u << 20) + (128u << 10));
  float* ob = qf;  // alias: qf raw dead after norm_kernel
  float* out = (float*)d_out;

  hipLaunchKernelGGL(qkv_kernel, dim3(768), dim3(256), 0, stream, input, w_qkv, qf, kf,
                     vfr, psum, psq);
  hipLaunchKernelGGL(norm_kernel, dim3(256), dim3(256), 0, stream, qf, kf, qfr_hi,
                     qfr_lo, kfr_hi, kfr_lo, psum, psq);
  hipLaunchKernelGGL(attn_kernel, dim3(512), dim3(512), 0, stream, qfr_hi, qfr_lo,
                     kfr_hi, kfr_lo, vfr, ob);
  hipLaunchKernelGGL(proj_kernel, dim3(1024), dim3(256), 0, stream, ob, w_out, b_out, out);
}